// Round 3
// baseline (111.356 us; speedup 1.0000x reference)
//
#include <hip/hip_runtime.h>

// out[b,k] = (WHT_2048(concat(x1[b],x2[b]))[k])^2 / 2048
// One wave (64 lanes) per row; 32 floats per lane.
// k = jo*256 + lane*4 + ji  (jo in [0,8), ji in [0,4))
//   k bits {0,1}   = ji   -> in-register stages (done per-chunk at load time)
//   k bits {2..5}  = lane bits 0..3 -> DPP stages (xor1,2,4,8)
//   k bits {6,7}   = lane bits 4,5  -> permlane16_swap / permlane32_swap pair stages
//   k bits {8,9,10}= jo   -> in-register stages (done last)
// Stages on disjoint bits commute, so this order equals the reference WHT.
//
// NOTE: plain cached loads/stores (nontemporal cost ~5.7us, round-1).
// NOTE: NO LDS-pipe ops at all — xor16 uses v_permlane16_swap_b32 (gfx950),
// removing 32 ds_swizzle + lgkmcnt waits from the butterfly chains (round-3).

typedef float f32x4 __attribute__((ext_vector_type(4)));
typedef unsigned int u32x2 __attribute__((ext_vector_type(2)));

template <int CTRL>
__device__ __forceinline__ float dpp_xmov(float x) {
    return __int_as_float(__builtin_amdgcn_update_dpp(
        0, __float_as_int(x), CTRL, 0xF, 0xF, true));
}

// Lane-xor stages for k bits 2..5 (lane bits 0..3), per element:
//   xor1: quad_perm [1,0,3,2]=0xB1 ; xor2: quad_perm [2,3,0,1]=0x4E
//   xor4 = xor3(0x1B) ∘ xor7(row_half_mirror 0x141)
//   xor8 = xor7(0x141) ∘ xor15(row_mirror 0x140)
__device__ __forceinline__ float lane_chain(float x, float s1, float s2,
                                            float s4, float s8) {
    x = fmaf(s1, x, dpp_xmov<0xB1>(x));
    x = fmaf(s2, x, dpp_xmov<0x4E>(x));
    x = fmaf(s4, x, dpp_xmov<0x141>(dpp_xmov<0x1B>(x)));
    x = fmaf(s8, x, dpp_xmov<0x140>(dpp_xmov<0x141>(x)));
    return x;
}

// xor32 butterfly on two registers via v_permlane32_swap (VALU pipe).
// swap(x,y): r0 = {x rows0-1, y rows0-1 ...}: r0[l]= l<32 ? x[l] : y[l^32];
// r1[l] = l<32 ? x[l^32] : y[l].  a=r0+r1 = {x'_lo, y'_lo}, b=r0-r1 =
// {x'_hi, y'_hi}; second swap redistributes: out = (x', y').
__device__ __forceinline__ void xor32_pair(float& x, float& y) {
    u32x2 r = __builtin_amdgcn_permlane32_swap(
        __float_as_uint(x), __float_as_uint(y), false, false);
    const float a = __uint_as_float(r[0]) + __uint_as_float(r[1]);
    const float b = __uint_as_float(r[0]) - __uint_as_float(r[1]);
    u32x2 r2 = __builtin_amdgcn_permlane32_swap(
        __float_as_uint(a), __float_as_uint(b), false, false);
    x = __uint_as_float(r2[0]);
    y = __uint_as_float(r2[1]);
}

// xor16 butterfly, same trick with v_permlane16_swap (odd 16-rows of x
// swap with even 16-rows of y): r0[l] = (l&16) ? y[l^16] : x[l];
// r1[l] = (l&16) ? y[l] : x[l^16].
// bit4=0 lanes: r0=x[l], r1=x[l^16] -> a=x[l]+x[l^16]=x'[l], b=x'[l^16].
// bit4=1 lanes: r0=y[l^16], r1=y[l] -> a=y'[l^16], b=y'[l].
// a = {x' on bit4=0, y'-partner on bit4=1}, b = {x'-partner, y'};
// second swap redistributes: out = (x', y').
__device__ __forceinline__ void xor16_pair(float& x, float& y) {
    u32x2 r = __builtin_amdgcn_permlane16_swap(
        __float_as_uint(x), __float_as_uint(y), false, false);
    const float a = __uint_as_float(r[0]) + __uint_as_float(r[1]);
    const float b = __uint_as_float(r[0]) - __uint_as_float(r[1]);
    u32x2 r2 = __builtin_amdgcn_permlane16_swap(
        __float_as_uint(a), __float_as_uint(b), false, false);
    x = __uint_as_float(r2[0]);
    y = __uint_as_float(r2[1]);
}

__global__ __launch_bounds__(256) void qf_wht_kernel(const float* __restrict__ x1,
                                                     const float* __restrict__ x2,
                                                     float* __restrict__ out,
                                                     int nrows) {
    const int wave = threadIdx.x >> 6;
    const int lane = threadIdx.x & 63;
    const int row  = blockIdx.x * 4 + wave;
    if (row >= nrows) return;

    const float s1  = (lane & 1)  ? -1.0f : 1.0f;
    const float s2  = (lane & 2)  ? -1.0f : 1.0f;
    const float s4  = (lane & 4)  ? -1.0f : 1.0f;
    const float s8  = (lane & 8)  ? -1.0f : 1.0f;

    // ---- issue all 8 loads up front (full MLP), cached ----
    const float* __restrict__ p1 = x1 + (size_t)row * 1024 + lane * 4;
    const float* __restrict__ p2 = x2 + (size_t)row * 1024 + lane * 4;
    f32x4 f[8];
#pragma unroll
    for (int jo = 0; jo < 4; ++jo)
        f[jo] = *reinterpret_cast<const f32x4*>(p1 + jo * 256);
#pragma unroll
    for (int jo = 4; jo < 8; ++jo)
        f[jo] = *reinterpret_cast<const f32x4*>(p2 + (jo - 4) * 256);

    // ---- per-chunk: bits {0,1} in-register, then all 6 lane stages ----
    // Each chunk only needs its own load back (descending vmcnt), so the
    // lane-stage chains overlap the remaining loads' latency.
    float v[32];
#pragma unroll
    for (int jo = 0; jo < 8; ++jo) {
        const float a01 = f[jo][0] + f[jo][1];
        const float d01 = f[jo][0] - f[jo][1];
        const float a23 = f[jo][2] + f[jo][3];
        const float d23 = f[jo][2] - f[jo][3];
        float c0 = a01 + a23;   // ji=0
        float c1 = d01 + d23;   // ji=1
        float c2 = a01 - a23;   // ji=2
        float c3 = d01 - d23;   // ji=3

        c0 = lane_chain(c0, s1, s2, s4, s8);
        c1 = lane_chain(c1, s1, s2, s4, s8);
        c2 = lane_chain(c2, s1, s2, s4, s8);
        c3 = lane_chain(c3, s1, s2, s4, s8);

        xor16_pair(c0, c1);
        xor16_pair(c2, c3);
        xor32_pair(c0, c1);
        xor32_pair(c2, c3);

        v[jo * 4 + 0] = c0;
        v[jo * 4 + 1] = c1;
        v[jo * 4 + 2] = c2;
        v[jo * 4 + 3] = c3;
    }

    // ---- k bits {8,9,10}: in-register butterflies across jo (j bits 2,3,4) ----
#pragma unroll
    for (int m = 4; m <= 16; m <<= 1) {
#pragma unroll
        for (int j = 0; j < 32; ++j) {
            if ((j & m) == 0) {
                const float a = v[j];
                const float b = v[j | m];
                v[j]     = a + b;
                v[j | m] = a - b;
            }
        }
    }

    // ---- square, scale, coalesced float4 stores ----
    const float scale = 1.0f / 2048.0f;
    float* __restrict__ po = out + (size_t)row * 2048 + lane * 4;
#pragma unroll
    for (int jo = 0; jo < 8; ++jo) {
        f32x4 o;
        o[0] = v[jo * 4 + 0] * v[jo * 4 + 0] * scale;
        o[1] = v[jo * 4 + 1] * v[jo * 4 + 1] * scale;
        o[2] = v[jo * 4 + 2] * v[jo * 4 + 2] * scale;
        o[3] = v[jo * 4 + 3] * v[jo * 4 + 3] * scale;
        *reinterpret_cast<f32x4*>(po + jo * 256) = o;
    }
}

extern "C" void kernel_launch(void* const* d_in, const int* in_sizes, int n_in,
                              void* d_out, int out_size, void* d_ws, size_t ws_size,
                              hipStream_t stream) {
    const float* x1 = (const float*)d_in[0];
    const float* x2 = (const float*)d_in[1];
    float* out = (float*)d_out;

    const int nrows = in_sizes[0] / 1024;           // 8192
    const int blocks = (nrows + 3) / 4;             // 4 rows per 256-thread block
    qf_wht_kernel<<<blocks, 256, 0, stream>>>(x1, x2, out, nrows);
}